// Round 4
// baseline (131.040 us; speedup 1.0000x reference)
//
#include <hip/hip_runtime.h>

#define NB 2
#define CIN 256
#define HH 64
#define WW 64
#define CCMP 64
#define HO 128
#define WO 128

// ---------------- k1: 1x1 conv x(2,256,64,64) -> comp(2,64,64,64) ----------------
// 512 blocks: (n, ccg of 16, hq of 16); 4 output channels per thread.
__global__ __launch_bounds__(256) void k1_comp(const float* __restrict__ x,
                                               const float* __restrict__ wc,
                                               const float* __restrict__ bc,
                                               float* __restrict__ comp) {
  int b = blockIdx.x;
  int n = b >> 8;
  int ccg = (b >> 4) & 15;
  int hq = b & 15;
  int hsub = threadIdx.x >> 6;
  int w = threadIdx.x & 63;
  int h = hq * 4 + hsub;
  float acc[4];
#pragma unroll
  for (int j = 0; j < 4; ++j) acc[j] = bc[ccg * 4 + j];
  const float* xp = x + ((size_t)(n * CIN) * HH + h) * WW + w;
#pragma unroll 4
  for (int c = 0; c < CIN; ++c) {
    float xv = xp[(size_t)c * HH * WW];
#pragma unroll
    for (int j = 0; j < 4; ++j) acc[j] += xv * wc[(ccg * 4 + j) * CIN + c];
  }
#pragma unroll
  for (int j = 0; j < 4; ++j)
    comp[((size_t)(n * CCMP + ccg * 4 + j) * HH + h) * WW + w] = acc[j];
}

// ------------- k2: fused 3x3 convs comp -> off(8ch) + ker(25ch), pad 1 -------------
// 1056 blocks: (n, oc of 33, hq of 16). One oc per block; weights staged in LDS.
__global__ __launch_bounds__(256) void k2_conv3(const float* __restrict__ comp,
                                                const float* __restrict__ w_off,
                                                const float* __restrict__ b_off,
                                                const float* __restrict__ w_ker,
                                                const float* __restrict__ b_ker,
                                                float* __restrict__ offb,
                                                float* __restrict__ kerb) {
  int b = blockIdx.x;
  int n = b / (33 * 16);
  int r = b % (33 * 16);
  int oc = r / 16;
  int hq = r % 16;
  int hsub = threadIdx.x >> 6;
  int w = threadIdx.x & 63;
  int h = hq * 4 + hsub;

  __shared__ float wl[CCMP * 9];
  const float* wsrc = (oc < 8) ? (w_off + (size_t)oc * CCMP * 9)
                               : (w_ker + (size_t)(oc - 8) * CCMP * 9);
  for (int i = threadIdx.x; i < CCMP * 9; i += 256) wl[i] = wsrc[i];
  __syncthreads();

  float acc = (oc < 8) ? b_off[oc] : b_ker[oc - 8];
  const float* cbase = comp + (size_t)n * CCMP * HH * WW;
#pragma unroll 4
  for (int c = 0; c < CCMP; ++c) {
    const float* cp = cbase + (size_t)c * HH * WW;
    const float* w9 = wl + c * 9;
#pragma unroll
    for (int dy = 0; dy < 3; ++dy) {
      int rr = h + dy - 1;
      if ((unsigned)rr < (unsigned)HH) {       // wave-uniform (h same across wave)
        const float* rowp = cp + rr * WW;
#pragma unroll
        for (int dx = 0; dx < 3; ++dx) {
          int cc = w + dx - 1;
          float v = ((unsigned)cc < (unsigned)WW) ? rowp[cc] : 0.f;
          acc += v * w9[dy * 3 + dx];
        }
      }
    }
  }
  if (oc < 8) offb[((size_t)(n * 8 + oc) * HH + h) * WW + w] = acc;
  else        kerb[((size_t)(n * 25 + (oc - 8)) * HH + h) * WW + w] = acc;
}

// ---------------- k3: softmax over the 25 ker channels, in place ----------------
__global__ void k3_softmax(float* __restrict__ kerb) {
  int t = blockIdx.x * 256 + threadIdx.x;  // 8192 threads
  int n = t >> 12;
  int pos = t & 4095;
  float v[25];
  float mx = -1e30f;
#pragma unroll
  for (int k = 0; k < 25; ++k) {
    v[k] = kerb[(size_t)(n * 25 + k) * 4096 + pos];
    mx = fmaxf(mx, v[k]);
  }
  float s = 0.f;
#pragma unroll
  for (int k = 0; k < 25; ++k) { v[k] = expf(v[k] - mx); s += v[k]; }
  float inv = 1.f / s;
#pragma unroll
  for (int k = 0; k < 25; ++k) kerb[(size_t)(n * 25 + k) * 4096 + pos] = v[k] * inv;
}

// ------- k4: bilinear-sample mask at offset positions -> wts(n,h,w,[pq],[k]) -------
__global__ void k4_wts(const float* __restrict__ offb, const float* __restrict__ mask,
                       float* __restrict__ wts) {
  int t = blockIdx.x * 256 + threadIdx.x;   // 32768 threads: (n, ho, wo)
  int n = t >> 14;
  int r = t & 16383;
  int ho = r >> 7;
  int wo = r & 127;
  int h = ho >> 1, p = ho & 1, w = wo >> 1, q = wo & 1;
  int pq = p * 2 + q;
  float offx = offb[((size_t)(n * 8 + pq) * HH + h) * WW + w];
  float offy = offb[((size_t)(n * 8 + 4 + pq) * HH + h) * WW + w];
  // align_corners=True + border clamp algebra reduces to sampling at (h+offy, w+offx)
  float ix = fminf(fmaxf((float)w + offx, 0.f), 63.f);
  float iy = fminf(fmaxf((float)h + offy, 0.f), 63.f);
  float x0f = floorf(ix), y0f = floorf(iy);
  float fx = ix - x0f, fy = iy - y0f;
  int x0 = (int)x0f, y0 = (int)y0f;
  int x1 = min(x0 + 1, 63), y1 = min(y0 + 1, 63);
  float w00 = (1.f - fx) * (1.f - fy), w01 = fx * (1.f - fy);
  float w10 = (1.f - fx) * fy,         w11 = fx * fy;
  float* wp = wts + ((((size_t)n * HH + h) * WW + w) * 4 + pq) * 25;
#pragma unroll
  for (int k = 0; k < 25; ++k) {
    const float* mp = mask + (size_t)(n * 25 + k) * 4096;
    wp[k] = mp[y0 * 64 + x0] * w00 + mp[y0 * 64 + x1] * w01 +
            mp[y1 * 64 + x0] * w10 + mp[y1 * 64 + x1] * w11;
  }
}

// -------- k5: out[n,c,2h+p,2w+q] = sum_k wt[n,h,w,pq,k] * x[n,c,h+ki-2,w+kj-2] --------
// lane = w (coalesced). Two half-passes (pq rows) with only 50 weights live -> no spill.
__global__ __launch_bounds__(256) void k5_out(const float* __restrict__ x,
                                              const float* __restrict__ wts,
                                              float* __restrict__ out) {
  int b = blockIdx.x;       // 1024 blocks: n(2) * h(64) * cg(8)
  int n = b >> 9;
  int r = b & 511;
  int h = r >> 3;
  int cg = r & 7;
  int wave = threadIdx.x >> 6;
  int w = threadIdx.x & 63;
  const float* wrow = wts + (((size_t)n * HH + h) * WW + w) * 100;
  int c0 = cg * 32 + wave * 8;   // 8 channels per wave

#pragma unroll
  for (int half = 0; half < 2; ++half) {
    // hoist 50 weights (pq = 2*half, 2*half+1) via 8B-aligned float2 loads
    float wt[50];
    const float2* wp2 = (const float2*)(wrow + half * 50);
#pragma unroll
    for (int i = 0; i < 25; ++i) {
      float2 v = wp2[i];
      wt[2 * i] = v.x; wt[2 * i + 1] = v.y;
    }
    for (int ci = 0; ci < 8; ++ci) {
      int c = c0 + ci;
      const float* xc = x + (size_t)(n * CIN + c) * HH * WW;
      float a0 = 0.f, a1 = 0.f;
#pragma unroll
      for (int dy = 0; dy < 5; ++dy) {
        int rr = h + dy - 2;
        bool rok = (unsigned)rr < (unsigned)HH;
        const float* xr = xc + rr * WW;
#pragma unroll
        for (int dx = 0; dx < 5; ++dx) {
          int cc = w + dx - 2;
          float xv = (rok && (unsigned)cc < (unsigned)WW) ? xr[cc] : 0.f;
          int k = dy * 5 + dx;
          a0 += wt[k] * xv;
          a1 += wt[25 + k] * xv;
        }
      }
      float2* o = (float2*)(out + ((size_t)(n * CIN + c) * HO + 2 * h + half) * WO + 2 * w);
      *o = make_float2(a0, a1);
    }
  }
}

extern "C" void kernel_launch(void* const* d_in, const int* in_sizes, int n_in,
                              void* d_out, int out_size, void* d_ws, size_t ws_size,
                              hipStream_t stream) {
  const float* x      = (const float*)d_in[0];
  const float* w_comp = (const float*)d_in[1];
  const float* b_comp = (const float*)d_in[2];
  const float* w_off  = (const float*)d_in[3];
  const float* b_off  = (const float*)d_in[4];
  const float* w_ker  = (const float*)d_in[5];
  const float* b_ker  = (const float*)d_in[6];
  float* out = (float*)d_out;

  float* ws   = (float*)d_ws;
  float* comp = ws;                       // 2*64*64*64   = 524288 floats
  float* offb = comp + 524288;            // 2*8*64*64    = 65536
  float* kerb = offb + 65536;             // 2*25*64*64   = 204800 (softmax in place)
  float* wts  = kerb + 204800;            // 2*64*64*100  = 819200 (16B-aligned)

  k1_comp<<<512, 256, 0, stream>>>(x, w_comp, b_comp, comp);
  k2_conv3<<<1056, 256, 0, stream>>>(comp, w_off, b_off, w_ker, b_ker, offb, kerb);
  k3_softmax<<<32, 256, 0, stream>>>(kerb);
  k4_wts<<<128, 256, 0, stream>>>(offb, kerb, wts);
  k5_out<<<1024, 256, 0, stream>>>(x, wts, out);
}

// Round 5
// 92.459 us; speedup vs baseline: 1.4173x; 1.4173x over previous
//
#include <hip/hip_runtime.h>

#define NB 2
#define CIN 256
#define HH 64
#define WW 64
#define CCMP 64
#define HO 128
#define WO 128

// padded comp layout: [n][c][66][66], interior at (+1,+1)
#define CPLD 66
#define CPCH (CPLD * CPLD)          // 4356
#define CPIMG (CCMP * CPCH)         // 278784
#define CPTOT (NB * CPIMG)          // 557568 floats

// ---------------- k1: 1x1 conv x(2,256,64,64) -> comp_pad interior ----------------
// 256 blocks: (n, ccg of 8, hq of 16); 8 output channels per thread.
__global__ __launch_bounds__(256) void k1_comp(const float* __restrict__ x,
                                               const float* __restrict__ wc,
                                               const float* __restrict__ bc,
                                               float* __restrict__ comp_pad) {
  int b = blockIdx.x;
  int n = b >> 7;
  int ccg = (b >> 4) & 7;
  int hq = b & 15;
  int hsub = threadIdx.x >> 6;
  int w = threadIdx.x & 63;
  int h = hq * 4 + hsub;
  float acc[8];
#pragma unroll
  for (int j = 0; j < 8; ++j) acc[j] = bc[ccg * 8 + j];
  const float* xp = x + ((size_t)(n * CIN) * HH + h) * WW + w;
#pragma unroll 4
  for (int c = 0; c < CIN; ++c) {
    float xv = xp[(size_t)c * HH * WW];
#pragma unroll
    for (int j = 0; j < 8; ++j) acc[j] += xv * wc[(ccg * 8 + j) * CIN + c];
  }
#pragma unroll
  for (int j = 0; j < 8; ++j)
    comp_pad[(size_t)n * CPIMG + (size_t)(ccg * 8 + j) * CPCH + (h + 1) * CPLD + (w + 1)] = acc[j];
}

// ------------- k2: fused 3x3 convs comp_pad -> off(8ch) + ker(25ch) -------------
// 544 blocks: (n, ocp of 17, hq of 16). 2 oc per thread; no bounds checks;
// c chunked by 4 -> 36 loads in flight then 72 FMAs; weights via uniform s_load.
__global__ __launch_bounds__(256) void k2_conv3(const float* __restrict__ comp_pad,
                                                const float* __restrict__ w_off,
                                                const float* __restrict__ b_off,
                                                const float* __restrict__ w_ker,
                                                const float* __restrict__ b_ker,
                                                float* __restrict__ offb,
                                                float* __restrict__ kerb) {
  int b = blockIdx.x;
  int n = b / (17 * 16);
  int r = b % (17 * 16);
  int ocp = r / 16;
  int hq = r % 16;
  int hsub = threadIdx.x >> 6;
  int w = threadIdx.x & 63;
  int h = hq * 4 + hsub;

  int oc0 = ocp * 2;
  int oc1 = (oc0 + 1 < 33) ? oc0 + 1 : 32;   // last block: duplicate oc 32 (benign)
  const float* wp0 = (oc0 < 8) ? (w_off + (size_t)oc0 * CCMP * 9)
                               : (w_ker + (size_t)(oc0 - 8) * CCMP * 9);
  const float* wp1 = (oc1 < 8) ? (w_off + (size_t)oc1 * CCMP * 9)
                               : (w_ker + (size_t)(oc1 - 8) * CCMP * 9);
  float a0 = (oc0 < 8) ? b_off[oc0] : b_ker[oc0 - 8];
  float a1 = (oc1 < 8) ? b_off[oc1] : b_ker[oc1 - 8];

  const float* base = comp_pad + (size_t)n * CPIMG + h * CPLD + w;  // tap(dy,dx)=base+c*CPCH+dy*CPLD+dx

  for (int cb = 0; cb < CCMP; cb += 4) {
    float t[4][9];
#pragma unroll
    for (int cc = 0; cc < 4; ++cc) {
      const float* p = base + (size_t)(cb + cc) * CPCH;
#pragma unroll
      for (int dy = 0; dy < 3; ++dy)
#pragma unroll
        for (int dx = 0; dx < 3; ++dx)
          t[cc][dy * 3 + dx] = p[dy * CPLD + dx];
    }
#pragma unroll
    for (int cc = 0; cc < 4; ++cc)
#pragma unroll
      for (int k = 0; k < 9; ++k) {
        float tv = t[cc][k];
        a0 += tv * wp0[(cb + cc) * 9 + k];
        a1 += tv * wp1[(cb + cc) * 9 + k];
      }
  }

  int pos = h * WW + w;
  if (oc0 < 8) offb[(size_t)(n * 8 + oc0) * 4096 + pos] = a0;
  else         kerb[(size_t)(n * 25 + (oc0 - 8)) * 4096 + pos] = a0;
  if (oc1 < 8) offb[(size_t)(n * 8 + oc1) * 4096 + pos] = a1;
  else         kerb[(size_t)(n * 25 + (oc1 - 8)) * 4096 + pos] = a1;
}

// ---------------- k3: softmax over the 25 ker channels, in place ----------------
__global__ void k3_softmax(float* __restrict__ kerb) {
  int t = blockIdx.x * 256 + threadIdx.x;  // 8192 threads
  int n = t >> 12;
  int pos = t & 4095;
  float v[25];
  float mx = -1e30f;
#pragma unroll
  for (int k = 0; k < 25; ++k) {
    v[k] = kerb[(size_t)(n * 25 + k) * 4096 + pos];
    mx = fmaxf(mx, v[k]);
  }
  float s = 0.f;
#pragma unroll
  for (int k = 0; k < 25; ++k) { v[k] = expf(v[k] - mx); s += v[k]; }
  float inv = 1.f / s;
#pragma unroll
  for (int k = 0; k < 25; ++k) kerb[(size_t)(n * 25 + k) * 4096 + pos] = v[k] * inv;
}

// ------- k4: bilinear-sample mask at offset positions -> wts(n,h,w,[pq],[k]) -------
__global__ void k4_wts(const float* __restrict__ offb, const float* __restrict__ mask,
                       float* __restrict__ wts) {
  int t = blockIdx.x * 256 + threadIdx.x;   // 32768 threads: (n, ho, wo)
  int n = t >> 14;
  int r = t & 16383;
  int ho = r >> 7;
  int wo = r & 127;
  int h = ho >> 1, p = ho & 1, w = wo >> 1, q = wo & 1;
  int pq = p * 2 + q;
  float offx = offb[((size_t)(n * 8 + pq) * HH + h) * WW + w];
  float offy = offb[((size_t)(n * 8 + 4 + pq) * HH + h) * WW + w];
  // align_corners=True + border clamp algebra reduces to sampling at (h+offy, w+offx)
  float ix = fminf(fmaxf((float)w + offx, 0.f), 63.f);
  float iy = fminf(fmaxf((float)h + offy, 0.f), 63.f);
  float x0f = floorf(ix), y0f = floorf(iy);
  float fx = ix - x0f, fy = iy - y0f;
  int x0 = (int)x0f, y0 = (int)y0f;
  int x1 = min(x0 + 1, 63), y1 = min(y0 + 1, 63);
  float w00 = (1.f - fx) * (1.f - fy), w01 = fx * (1.f - fy);
  float w10 = (1.f - fx) * fy,         w11 = fx * fy;
  float* wp = wts + ((((size_t)n * HH + h) * WW + w) * 4 + pq) * 25;
#pragma unroll
  for (int k = 0; k < 25; ++k) {
    const float* mp = mask + (size_t)(n * 25 + k) * 4096;
    wp[k] = mp[y0 * 64 + x0] * w00 + mp[y0 * 64 + x1] * w01 +
            mp[y1 * 64 + x0] * w10 + mp[y1 * 64 + x1] * w11;
  }
}

// -------- k5: out[n,c,2h+p,2w+q] = sum_k wt[n,h,w,pq,k] * x[n,c,h+ki-2,w+kj-2] --------
// lane = w (coalesced). Two half-passes (pq rows) with only 50 weights live -> no spill.
__global__ __launch_bounds__(256) void k5_out(const float* __restrict__ x,
                                              const float* __restrict__ wts,
                                              float* __restrict__ out) {
  int b = blockIdx.x;       // 1024 blocks: n(2) * h(64) * cg(8)
  int n = b >> 9;
  int r = b & 511;
  int h = r >> 3;
  int cg = r & 7;
  int wave = threadIdx.x >> 6;
  int w = threadIdx.x & 63;
  const float* wrow = wts + (((size_t)n * HH + h) * WW + w) * 100;
  int c0 = cg * 32 + wave * 8;   // 8 channels per wave

#pragma unroll
  for (int half = 0; half < 2; ++half) {
    // hoist 50 weights (pq = 2*half, 2*half+1) via 8B-aligned float2 loads
    float wt[50];
    const float2* wp2 = (const float2*)(wrow + half * 50);
#pragma unroll
    for (int i = 0; i < 25; ++i) {
      float2 v = wp2[i];
      wt[2 * i] = v.x; wt[2 * i + 1] = v.y;
    }
    for (int ci = 0; ci < 8; ++ci) {
      int c = c0 + ci;
      const float* xc = x + (size_t)(n * CIN + c) * HH * WW;
      float a0 = 0.f, a1 = 0.f;
#pragma unroll
      for (int dy = 0; dy < 5; ++dy) {
        int rr = h + dy - 2;
        bool rok = (unsigned)rr < (unsigned)HH;
        const float* xr = xc + rr * WW;
#pragma unroll
        for (int dx = 0; dx < 5; ++dx) {
          int cc = w + dx - 2;
          float xv = (rok && (unsigned)cc < (unsigned)WW) ? xr[cc] : 0.f;
          int k = dy * 5 + dx;
          a0 += wt[k] * xv;
          a1 += wt[25 + k] * xv;
        }
      }
      float2* o = (float2*)(out + ((size_t)(n * CIN + c) * HO + 2 * h + half) * WO + 2 * w);
      *o = make_float2(a0, a1);
    }
  }
}

extern "C" void kernel_launch(void* const* d_in, const int* in_sizes, int n_in,
                              void* d_out, int out_size, void* d_ws, size_t ws_size,
                              hipStream_t stream) {
  const float* x      = (const float*)d_in[0];
  const float* w_comp = (const float*)d_in[1];
  const float* b_comp = (const float*)d_in[2];
  const float* w_off  = (const float*)d_in[3];
  const float* b_off  = (const float*)d_in[4];
  const float* w_ker  = (const float*)d_in[5];
  const float* b_ker  = (const float*)d_in[6];
  float* out = (float*)d_out;

  float* ws       = (float*)d_ws;
  float* comp_pad = ws;                        // 557568 floats (2*64*66*66)
  float* offb     = comp_pad + CPTOT;          // 65536
  float* kerb     = offb + 65536;              // 204800 (softmax in place)
  float* wts      = kerb + 204800;             // 819200

  hipMemsetAsync(comp_pad, 0, (size_t)CPTOT * sizeof(float), stream);  // zero halo
  k1_comp<<<256, 256, 0, stream>>>(x, w_comp, b_comp, comp_pad);
  k2_conv3<<<544, 256, 0, stream>>>(comp_pad, w_off, b_off, w_ker, b_ker, offb, kerb);
  k3_softmax<<<32, 256, 0, stream>>>(kerb);
  k4_wts<<<128, 256, 0, stream>>>(offb, kerb, wts);
  k5_out<<<1024, 256, 0, stream>>>(x, wts, out);
}

// Round 6
// 92.367 us; speedup vs baseline: 1.4187x; 1.0010x over previous
//
#include <hip/hip_runtime.h>

#define NB 2
#define CIN 256
#define HH 64
#define WW 64
#define CCMP 64
#define HO 128
#define WO 128

// padded comp layout: [n][c][66][66], interior at (+1,+1)
#define CPLD 66
#define CPCH (CPLD * CPLD)          // 4356
#define CPIMG (CCMP * CPCH)         // 278784
#define CPTOT (NB * CPIMG)          // 557568 floats

// ---------------- k0: zero only the halo of comp_pad (260 elems/plane) ----------------
__global__ __launch_bounds__(256) void k0_halo(float* __restrict__ comp_pad) {
  int img = blockIdx.x;            // 128 blocks: n*CCMP + c
  float* p = comp_pad + (size_t)img * CPCH;
  for (int i = threadIdx.x; i < 260; i += 256) {
    if (i < 66)       p[i] = 0.f;                            // top row
    else if (i < 132) p[65 * CPLD + (i - 66)] = 0.f;         // bottom row
    else if (i < 196) p[(i - 131) * CPLD] = 0.f;             // left col rows 1..64
    else              p[(i - 195) * CPLD + 65] = 0.f;        // right col rows 1..64
  }
}

// ---------------- k1: 1x1 conv x(2,256,64,64) -> comp_pad interior ----------------
// 256 blocks: (n, ccg of 8, hq of 16); 8 output channels per thread.
__global__ __launch_bounds__(256) void k1_comp(const float* __restrict__ x,
                                               const float* __restrict__ wc,
                                               const float* __restrict__ bc,
                                               float* __restrict__ comp_pad) {
  int b = blockIdx.x;
  int n = b >> 7;
  int ccg = (b >> 4) & 7;
  int hq = b & 15;
  int hsub = threadIdx.x >> 6;
  int w = threadIdx.x & 63;
  int h = hq * 4 + hsub;
  float acc[8];
#pragma unroll
  for (int j = 0; j < 8; ++j) acc[j] = bc[ccg * 8 + j];
  const float* xp = x + ((size_t)(n * CIN) * HH + h) * WW + w;
#pragma unroll 4
  for (int c = 0; c < CIN; ++c) {
    float xv = xp[(size_t)c * HH * WW];
#pragma unroll
    for (int j = 0; j < 8; ++j) acc[j] += xv * wc[(ccg * 8 + j) * CIN + c];
  }
#pragma unroll
  for (int j = 0; j < 8; ++j)
    comp_pad[(size_t)n * CPIMG + (size_t)(ccg * 8 + j) * CPCH + (h + 1) * CPLD + (w + 1)] = acc[j];
}

// ------------- k2: fused 3x3 convs comp_pad -> off(8ch) + ker(25ch) -------------
// 544 blocks: (n, ocp of 17, hq of 16). 2 oc per thread; no bounds checks;
// c chunked by 4 -> 36 loads in flight then 72 FMAs; weights via uniform s_load.
__global__ __launch_bounds__(256) void k2_conv3(const float* __restrict__ comp_pad,
                                                const float* __restrict__ w_off,
                                                const float* __restrict__ b_off,
                                                const float* __restrict__ w_ker,
                                                const float* __restrict__ b_ker,
                                                float* __restrict__ offb,
                                                float* __restrict__ kerb) {
  int b = blockIdx.x;
  int n = b / (17 * 16);
  int r = b % (17 * 16);
  int ocp = r / 16;
  int hq = r % 16;
  int hsub = threadIdx.x >> 6;
  int w = threadIdx.x & 63;
  int h = hq * 4 + hsub;

  int oc0 = ocp * 2;
  int oc1 = (oc0 + 1 < 33) ? oc0 + 1 : 32;   // last block: duplicate oc 32 (benign)
  const float* wp0 = (oc0 < 8) ? (w_off + (size_t)oc0 * CCMP * 9)
                               : (w_ker + (size_t)(oc0 - 8) * CCMP * 9);
  const float* wp1 = (oc1 < 8) ? (w_off + (size_t)oc1 * CCMP * 9)
                               : (w_ker + (size_t)(oc1 - 8) * CCMP * 9);
  float a0 = (oc0 < 8) ? b_off[oc0] : b_ker[oc0 - 8];
  float a1 = (oc1 < 8) ? b_off[oc1] : b_ker[oc1 - 8];

  const float* base = comp_pad + (size_t)n * CPIMG + h * CPLD + w;  // tap(dy,dx)=base+c*CPCH+dy*CPLD+dx

  for (int cb = 0; cb < CCMP; cb += 4) {
    float t[4][9];
#pragma unroll
    for (int cc = 0; cc < 4; ++cc) {
      const float* p = base + (size_t)(cb + cc) * CPCH;
#pragma unroll
      for (int dy = 0; dy < 3; ++dy)
#pragma unroll
        for (int dx = 0; dx < 3; ++dx)
          t[cc][dy * 3 + dx] = p[dy * CPLD + dx];
    }
#pragma unroll
    for (int cc = 0; cc < 4; ++cc)
#pragma unroll
      for (int k = 0; k < 9; ++k) {
        float tv = t[cc][k];
        a0 += tv * wp0[(cb + cc) * 9 + k];
        a1 += tv * wp1[(cb + cc) * 9 + k];
      }
  }

  int pos = h * WW + w;
  if (oc0 < 8) offb[(size_t)(n * 8 + oc0) * 4096 + pos] = a0;
  else         kerb[(size_t)(n * 25 + (oc0 - 8)) * 4096 + pos] = a0;
  if (oc1 < 8) offb[(size_t)(n * 8 + oc1) * 4096 + pos] = a1;
  else         kerb[(size_t)(n * 25 + (oc1 - 8)) * 4096 + pos] = a1;
}

// ---------------- k3: softmax over the 25 ker channels, in place ----------------
__global__ void k3_softmax(float* __restrict__ kerb) {
  int t = blockIdx.x * 256 + threadIdx.x;  // 8192 threads
  int n = t >> 12;
  int pos = t & 4095;
  float v[25];
  float mx = -1e30f;
#pragma unroll
  for (int k = 0; k < 25; ++k) {
    v[k] = kerb[(size_t)(n * 25 + k) * 4096 + pos];
    mx = fmaxf(mx, v[k]);
  }
  float s = 0.f;
#pragma unroll
  for (int k = 0; k < 25; ++k) { v[k] = expf(v[k] - mx); s += v[k]; }
  float inv = 1.f / s;
#pragma unroll
  for (int k = 0; k < 25; ++k) kerb[(size_t)(n * 25 + k) * 4096 + pos] = v[k] * inv;
}

// ------- k4: bilinear-sample mask at offset positions -> wts(n,h,w,[pq],[k]) -------
__global__ void k4_wts(const float* __restrict__ offb, const float* __restrict__ mask,
                       float* __restrict__ wts) {
  int t = blockIdx.x * 256 + threadIdx.x;   // 32768 threads: (n, ho, wo)
  int n = t >> 14;
  int r = t & 16383;
  int ho = r >> 7;
  int wo = r & 127;
  int h = ho >> 1, p = ho & 1, w = wo >> 1, q = wo & 1;
  int pq = p * 2 + q;
  float offx = offb[((size_t)(n * 8 + pq) * HH + h) * WW + w];
  float offy = offb[((size_t)(n * 8 + 4 + pq) * HH + h) * WW + w];
  // align_corners=True + border clamp algebra reduces to sampling at (h+offy, w+offx)
  float ix = fminf(fmaxf((float)w + offx, 0.f), 63.f);
  float iy = fminf(fmaxf((float)h + offy, 0.f), 63.f);
  float x0f = floorf(ix), y0f = floorf(iy);
  float fx = ix - x0f, fy = iy - y0f;
  int x0 = (int)x0f, y0 = (int)y0f;
  int x1 = min(x0 + 1, 63), y1 = min(y0 + 1, 63);
  float w00 = (1.f - fx) * (1.f - fy), w01 = fx * (1.f - fy);
  float w10 = (1.f - fx) * fy,         w11 = fx * fy;
  float* wp = wts + ((((size_t)n * HH + h) * WW + w) * 4 + pq) * 25;
#pragma unroll
  for (int k = 0; k < 25; ++k) {
    const float* mp = mask + (size_t)(n * 25 + k) * 4096;
    wp[k] = mp[y0 * 64 + x0] * w00 + mp[y0 * 64 + x1] * w01 +
            mp[y1 * 64 + x0] * w10 + mp[y1 * 64 + x1] * w11;
  }
}

// -------- k5: out[n,c,2h+p,2w+q] = sum_k wt[n,h,w,pq,k] * x[n,c,h+ki-2,w+kj-2] --------
// lane = w (coalesced). Two half-passes (pq rows) with only 50 weights live -> no spill.
__global__ __launch_bounds__(256) void k5_out(const float* __restrict__ x,
                                              const float* __restrict__ wts,
                                              float* __restrict__ out) {
  int b = blockIdx.x;       // 1024 blocks: n(2) * h(64) * cg(8)
  int n = b >> 9;
  int r = b & 511;
  int h = r >> 3;
  int cg = r & 7;
  int wave = threadIdx.x >> 6;
  int w = threadIdx.x & 63;
  const float* wrow = wts + (((size_t)n * HH + h) * WW + w) * 100;
  int c0 = cg * 32 + wave * 8;   // 8 channels per wave

#pragma unroll
  for (int half = 0; half < 2; ++half) {
    // hoist 50 weights (pq = 2*half, 2*half+1) via 8B-aligned float2 loads
    float wt[50];
    const float2* wp2 = (const float2*)(wrow + half * 50);
#pragma unroll
    for (int i = 0; i < 25; ++i) {
      float2 v = wp2[i];
      wt[2 * i] = v.x; wt[2 * i + 1] = v.y;
    }
    for (int ci = 0; ci < 8; ++ci) {
      int c = c0 + ci;
      const float* xc = x + (size_t)(n * CIN + c) * HH * WW;
      float a0 = 0.f, a1 = 0.f;
#pragma unroll
      for (int dy = 0; dy < 5; ++dy) {
        int rr = h + dy - 2;
        bool rok = (unsigned)rr < (unsigned)HH;
        const float* xr = xc + rr * WW;
#pragma unroll
        for (int dx = 0; dx < 5; ++dx) {
          int cc = w + dx - 2;
          float xv = (rok && (unsigned)cc < (unsigned)WW) ? xr[cc] : 0.f;
          int k = dy * 5 + dx;
          a0 += wt[k] * xv;
          a1 += wt[25 + k] * xv;
        }
      }
      float2* o = (float2*)(out + ((size_t)(n * CIN + c) * HO + 2 * h + half) * WO + 2 * w);
      *o = make_float2(a0, a1);
    }
  }
}

extern "C" void kernel_launch(void* const* d_in, const int* in_sizes, int n_in,
                              void* d_out, int out_size, void* d_ws, size_t ws_size,
                              hipStream_t stream) {
  const float* x      = (const float*)d_in[0];
  const float* w_comp = (const float*)d_in[1];
  const float* b_comp = (const float*)d_in[2];
  const float* w_off  = (const float*)d_in[3];
  const float* b_off  = (const float*)d_in[4];
  const float* w_ker  = (const float*)d_in[5];
  const float* b_ker  = (const float*)d_in[6];
  float* out = (float*)d_out;

  float* ws       = (float*)d_ws;
  float* comp_pad = ws;                        // 557568 floats (2*64*66*66)
  float* offb     = comp_pad + CPTOT;          // 65536
  float* kerb     = offb + 65536;              // 204800 (softmax in place)
  float* wts      = kerb + 204800;             // 819200

  k0_halo<<<NB * CCMP, 256, 0, stream>>>(comp_pad);
  k1_comp<<<256, 256, 0, stream>>>(x, w_comp, b_comp, comp_pad);
  k2_conv3<<<544, 256, 0, stream>>>(comp_pad, w_off, b_off, w_ker, b_ker, offb, kerb);
  k3_softmax<<<32, 256, 0, stream>>>(kerb);
  k4_wts<<<128, 256, 0, stream>>>(offb, kerb, wts);
  k5_out<<<1024, 256, 0, stream>>>(x, wts, out);
}